// Round 1
// baseline (537.166 us; speedup 1.0000x reference)
//
#include <hip/hip_runtime.h>
#include <hip/hip_bf16.h>

#define NV 23
#define NC 256
#define NTOT 16384
#define FLAT (NV * NC)     // 5888
#define FLAT4 (FLAT / 4)   // 1472

typedef short s16x8 __attribute__((ext_vector_type(8)));  // 8 bf16 bit-patterns (4 VGPRs)
typedef float f32x4 __attribute__((ext_vector_type(4)));

// x/23 for 0 <= x < 61681 (magic = ceil(2^20/23))
__device__ __forceinline__ int divNV(int x) {
  return (int)(((unsigned)x * 45591u) >> 20);
}
// f32 -> bf16 bits, round-to-nearest-even
__device__ __forceinline__ unsigned short f2bf(float f) {
  unsigned u = __float_as_uint(f);
  u += 0x7fffu + ((u >> 16) & 1u);
  return (unsigned short)(u >> 16);
}

// ws layout (bytes):
//   0       : Wt  short[65536]  (W transposed to [d][c], bf16)   131072
//   131072  : m2  float[5888]   (tanh(mask)+1)                    23552
//   154624  : sum float[5888]                                     23552
//   178176  : ssq float[5888]                                     23552
//   201728  : An2 float[5888]   (j-indexed scale)                 23552
//   225280  : Bn2 float[5888]   (j-indexed shift)                 23552

__global__ void k_prep(const float* __restrict__ W, const float* __restrict__ mask,
                       short* __restrict__ Wt, float* __restrict__ m2,
                       float* __restrict__ sums) {
  int idx = blockIdx.x * 256 + threadIdx.x;  // grid 256 -> 65536
  int d = idx >> 8, c = idx & 255;
  Wt[idx] = (short)f2bf(W[c * 256 + d]);
  if (idx < FLAT) m2[idx] = tanhf(mask[idx]) + 1.0f;
  if (idx < 2 * FLAT) sums[idx] = 0.0f;  // zero sum+ssq (contiguous)
}

__global__ void k_finalize(const float* __restrict__ sum, const float* __restrict__ ssq,
                           const float* __restrict__ bnw, const float* __restrict__ bnb,
                           float* __restrict__ An2, float* __restrict__ Bn2) {
  int idx = blockIdx.x * 256 + threadIdx.x;  // (w,d) feature in y-space
  if (idx >= FLAT) return;
  int w = idx >> 8, d = idx & 255;
  float mean = sum[idx] * (1.0f / NTOT);
  float var  = ssq[idx] * (1.0f / NTOT) - mean * mean;
  float inv  = rsqrtf(var + 1e-5f);
  int i = w + d; i -= NV * divNV(i);          // out-shift row: i = (w+d) % 23
  float a = inv * bnw[i * 256 + d];
  int j = d * NV + i;                          // flat out index within slab
  An2[j] = a;
  Bn2[j] = bnb[i * 256 + d] - mean * a;
}

// WRITE=0: stats pass (accumulate sum/ssq of y).  WRITE=1: recompute + normalize + residual + relu.
template <int WRITE>
__global__ __launch_bounds__(512) void k_gemm(
    const float* __restrict__ x0, const short* __restrict__ Wt,
    const float* __restrict__ m2, float* __restrict__ sum, float* __restrict__ ssq,
    const float* __restrict__ An2, const float* __restrict__ Bn2,
    float* __restrict__ out, int nb) {
  extern __shared__ char smem[];
  float* slab = (float*)(smem + 16384);            // x0 slab (WRITE only), 23552 B
  float* obuf = (float*)(smem + 16384 + 23552);    // y staging (WRITE only), 23552 B

  const int tid = threadIdx.x;
  const int lane = tid & 63;
  const int wv = tid >> 6;     // wave 0..7, owns d-strip [wv*32, wv*32+32)
  const int l15 = lane & 15;
  const int lg = lane >> 4;    // k-group 0..3
  const int d0 = wv * 32;

  // B fragments (register-resident for whole block): B[k=c][n=d] = Wt[d][c], k-contiguous
  s16x8 bfr[2][8];
#pragma unroll
  for (int nt = 0; nt < 2; ++nt)
#pragma unroll
    for (int kt = 0; kt < 8; ++kt)
      bfr[nt][kt] = *(const s16x8*)(Wt + (d0 + nt * 16 + l15) * 256 + kt * 32 + lg * 8);

  // zero X' pad rows 23..31 (never written by formation)
  for (int i = tid; i < 1152; i += 512)
    ((int*)(smem + NV * 512))[i] = 0;

  float s1[2][2][4], s2[2][2][4];
  if (!WRITE) {
#pragma unroll
    for (int mt = 0; mt < 2; ++mt)
#pragma unroll
      for (int nt = 0; nt < 2; ++nt)
#pragma unroll
        for (int r = 0; r < 4; ++r) { s1[mt][nt][r] = 0.f; s2[mt][nt][r] = 0.f; }
  }

  const int n_base = blockIdx.x * nb;
  for (int t = 0; t < nb; ++t) {
    const int n = n_base + t;
    const f32x4* xg = (const f32x4*)(x0 + (size_t)n * FLAT);

    // ---- formation: X'[w][c] = x0[n,c,(w+c)%23] * m2[w,c], bf16, XOR-swizzled LDS ----
    for (int i = tid; i < FLAT4; i += 512) {
      f32x4 xv = xg[i];
      if (WRITE) *(f32x4*)(slab + i * 4) = xv;   // keep raw slab for residual
      int p = i * 4;
      int c = divNV(p);
      int v = p - c * NV;
      int cm = c - NV * divNV(c);
#pragma unroll
      for (int e = 0; e < 4; ++e) {
        int w = v - cm; w += (w >> 31) & NV;      // (v - c) mod 23
        float val = xv[e] * m2[(w << 8) + c];
        int off = (w << 9) + ((c << 1) ^ ((w & 7) << 4));
        *(short*)(smem + off) = (short)f2bf(val);
        ++v;
        if (v == NV) { v = 0; ++c; ++cm; if (cm == NV) cm = 0; }
      }
    }
    __syncthreads();

    // ---- MFMA: y[w,d] = sum_c X'[w,c] * W[c,d] ----
    f32x4 acc[2][2];
#pragma unroll
    for (int mt = 0; mt < 2; ++mt)
#pragma unroll
      for (int nt = 0; nt < 2; ++nt)
        acc[mt][nt] = (f32x4){0.f, 0.f, 0.f, 0.f};
#pragma unroll
    for (int kt = 0; kt < 8; ++kt) {
      s16x8 af[2];
#pragma unroll
      for (int mt = 0; mt < 2; ++mt) {
        int row = mt * 16 + l15;
        int off = (row << 9) + (((kt * 32 + lg * 8) << 1) ^ ((row & 7) << 4));
        af[mt] = *(const s16x8*)(smem + off);
      }
#pragma unroll
      for (int mt = 0; mt < 2; ++mt)
#pragma unroll
        for (int nt = 0; nt < 2; ++nt)
          acc[mt][nt] = __builtin_amdgcn_mfma_f32_16x16x32_bf16(
              af[mt], bfr[nt][kt], acc[mt][nt], 0, 0, 0);
    }
    __syncthreads();  // X' reads done before next formation

    if (!WRITE) {
#pragma unroll
      for (int mt = 0; mt < 2; ++mt)
#pragma unroll
        for (int nt = 0; nt < 2; ++nt)
#pragma unroll
          for (int r = 0; r < 4; ++r) {
            float y = acc[mt][nt][r];
            s1[mt][nt][r] += y;
            s2[mt][nt][r] += y * y;
          }
    } else {
      // stage y into obuf at out-shifted flat position j = d*23 + (w+d)%23
#pragma unroll
      for (int mt = 0; mt < 2; ++mt)
#pragma unroll
        for (int nt = 0; nt < 2; ++nt)
#pragma unroll
          for (int r = 0; r < 4; ++r) {
            int w = mt * 16 + lg * 4 + r;   // C/D layout: row = (lane>>4)*4 + reg
            if (w < NV) {
              int d = d0 + nt * 16 + l15;   // col = lane & 15
              int s = w + d; s -= NV * divNV(s);
              obuf[d * NV + s] = acc[mt][nt][r];
            }
          }
      __syncthreads();
      // coalesced epilogue: normalize (flat A/B tables), residual, relu
      f32x4* og = (f32x4*)(out + (size_t)n * FLAT);
      const f32x4* a4 = (const f32x4*)An2;
      const f32x4* b4 = (const f32x4*)Bn2;
      for (int i = tid; i < FLAT4; i += 512) {
        f32x4 y = *(const f32x4*)(obuf + i * 4);
        f32x4 sl = *(const f32x4*)(slab + i * 4);
        f32x4 av = a4[i];
        f32x4 bv = b4[i];
        f32x4 o;
#pragma unroll
        for (int e = 0; e < 4; ++e)
          o[e] = fmaxf(y[e] * av[e] + bv[e] + sl[e], 0.0f);
        og[i] = o;
      }
      __syncthreads();  // obuf/slab consumed before next n
    }
  }

  if (!WRITE) {
#pragma unroll
    for (int mt = 0; mt < 2; ++mt)
#pragma unroll
      for (int nt = 0; nt < 2; ++nt)
#pragma unroll
        for (int r = 0; r < 4; ++r) {
          int w = mt * 16 + lg * 4 + r;
          if (w < NV) {
            int d = d0 + nt * 16 + l15;
            atomicAdd(sum + (w << 8) + d, s1[mt][nt][r]);
            atomicAdd(ssq + (w << 8) + d, s2[mt][nt][r]);
          }
        }
  }
}

extern "C" void kernel_launch(void* const* d_in, const int* in_sizes, int n_in,
                              void* d_out, int out_size, void* d_ws, size_t ws_size,
                              hipStream_t stream) {
  const float* x0   = (const float*)d_in[0];
  const float* W    = (const float*)d_in[1];
  // d_in[2] = bias: constant over n, cancels inside BN's (x - mean) -> unused
  const float* mask = (const float*)d_in[3];
  const float* bnw  = (const float*)d_in[4];
  const float* bnb  = (const float*)d_in[5];
  // d_in[6], d_in[7] = shift tables: folded into addressing
  float* out = (float*)d_out;

  char* ws = (char*)d_ws;
  short* Wt  = (short*)ws;
  float* m2  = (float*)(ws + 131072);
  float* sum = (float*)(ws + 154624);
  float* ssq = (float*)(ws + 178176);
  float* An2 = (float*)(ws + 201728);
  float* Bn2 = (float*)(ws + 225280);

  k_prep<<<256, 256, 0, stream>>>(W, mask, Wt, m2, sum);
  k_gemm<0><<<512, 512, 16384, stream>>>(x0, Wt, m2, sum, ssq, nullptr, nullptr, nullptr, 32);
  k_finalize<<<23, 256, 0, stream>>>(sum, ssq, bnw, bnb, An2, Bn2);
  k_gemm<1><<<1024, 512, 16384 + 2 * 23552, stream>>>(x0, Wt, m2, sum, ssq, An2, Bn2, out, 16);
}